// Round 3
// baseline (224.929 us; speedup 1.0000x reference)
//
#include <hip/hip_runtime.h>
#include <hip/hip_bf16.h>
#include <stdint.h>

typedef __attribute__((ext_vector_type(8))) short bf16x8;
typedef __attribute__((ext_vector_type(4))) float f32x4;
typedef __attribute__((ext_vector_type(16))) float f32x16;

#define MFMA16(a,b,c) __builtin_amdgcn_mfma_f32_16x16x32_bf16((a),(b),(c),0,0,0)
#define MFMA32(a,b,c) __builtin_amdgcn_mfma_f32_32x32x16_bf16((a),(b),(c),0,0,0)
#define AS1 __attribute__((address_space(1)))
#define AS3 __attribute__((address_space(3)))

__device__ inline short f2bf(float f) {
    union { __hip_bfloat16 h; short s; } u;
    u.h = __float2bfloat16(f);
    return u.s;
}
__device__ inline uint32_t pack_bf16(float a, float b) {
    union { __hip_bfloat16 h; uint16_t u; } ua, ub;
    ua.h = __float2bfloat16(a); ub.h = __float2bfloat16(b);
    return (uint32_t)ua.u | ((uint32_t)ub.u << 16);
}

// cross-half register exchange
#if __has_builtin(__builtin_amdgcn_permlane32_swap)
#define SWAP32(x, y, a, b) { auto _r = __builtin_amdgcn_permlane32_swap((a),(b),false,false); \
                             (x) = _r[0]; (y) = _r[1]; }
#else
#define SWAP32(x, y, a, b) { uint32_t _ta = __shfl_xor((uint32_t)(a),32); \
                             uint32_t _tb = __shfl_xor((uint32_t)(b),32); \
                             (x) = hh_ ? _tb : (a); (y) = hh_ ? (b) : _ta; }
#endif

// S' = S * scale * log2(e): fold into Wq so attention exp is native exp2.
#define QSCALE 0.12751879523879295f   // (1/sqrt(128)) * log2(e)

// ---------------------------------------------------------------------------
// Kernel 1: eff-weight mix -> bf16 W [3][8][128][512]; x f32 -> bf16
// ---------------------------------------------------------------------------
#define NW (8*128*512)        // 524288 per projection
#define NX4 (8192*512/4)      // 1048576 float4 chunks of x

__global__ void prep_kernel(const float* __restrict__ x,
                            const float* __restrict__ w,
                            const float* __restrict__ bK,
                            const float* __restrict__ bQ,
                            const float* __restrict__ bV,
                            short* __restrict__ xb,    // [8192][512]
                            short* __restrict__ W)     // [3][1024][512]  (K,Q,V)
{
    const float w0 = w[0], w1 = w[1], w2 = w[2], w3 = w[3];
    for (int i = blockIdx.x * blockDim.x + threadIdx.x; i < NW + NX4;
         i += gridDim.x * blockDim.x) {
        if (i < NW) {
            int e = i & 511;
            int d = (i >> 9) & 127;
            int h = i >> 16;
            float eff = 0.f;
            if (h < 4) { eff += w2; if (d < 64 && e < 256) eff += w0; }
            if (d < 32 && e < 256) eff += w1;
            if (d < 64) eff += w3;
            W[i]          = f2bf(eff * bK[i]);
            W[i + NW]     = f2bf(eff * bQ[i] * QSCALE);
            W[i + 2*NW]   = f2bf(eff * bV[i]);
        } else {
            int j = i - NW;
            float4 v = ((const float4*)x)[j];
            short4 o;
            o.x = f2bf(v.x); o.y = f2bf(v.y); o.z = f2bf(v.z); o.w = f2bf(v.w);
            ((short4*)xb)[j] = o;
        }
    }
}

// ---------------------------------------------------------------------------
// Kernel 2: C[8192,3072] = xb[8192,512] @ W[3072,512]^T
// K,Q stored [bh][t][d]; V stored TRANSPOSED as [bh][d][t].
// LDS-repacked coalesced epilogue; bijective XCD grid swizzle.
// ---------------------------------------------------------------------------
__global__ __launch_bounds__(256)
void proj_gemm(const short* __restrict__ A,    // [8192][512]
               const short* __restrict__ Bw,   // [3072][512]
               short* __restrict__ qkv)
{
    __shared__ short S[128 * 128];             // 32 KB: staging + repack
    short* As = S;                             // 16 KB
    short* Bs = S + 128 * 64;                  // 16 KB
    const int tid = threadIdx.x;
    const int lane = tid & 63;
    const int wave = tid >> 6;
    const int wr = wave >> 1, wc = wave & 1;
    const int l15 = lane & 15, lk = lane >> 4;

    // bijective XCD swizzle: 1536 blocks, 192 consecutive per XCD
    const int wg = (blockIdx.x & 7) * 192 + (blockIdx.x >> 3);
    const int bm = (wg / 24) * 128;
    const int bn = (wg % 24) * 128;

    char* Ab = (char*)As;
    char* Bb = (char*)Bs;
    char* Sb = (char*)S;
    f32x4 acc[4][4] = {};

    for (int k0 = 0; k0 < 512; k0 += 64) {
        __syncthreads();
#pragma unroll
        for (int i = 0; i < 4; ++i) {
            int c = i * 256 + tid;              // 0..1023, 16B chunk
            int lin = c * 16;                   // linear byte in 16 KB tile
            int row = lin >> 7;                 // 0..127
            int cof = ((lin & 127) ^ ((row & 7) << 4)) >> 1;   // shorts
            __builtin_amdgcn_global_load_lds(
                (const AS1 void*)(A + (size_t)(bm + row) * 512 + k0 + cof),
                (AS3 void*)(As + c * 8), 16, 0, 0);
            __builtin_amdgcn_global_load_lds(
                (const AS1 void*)(Bw + (size_t)(bn + row) * 512 + k0 + cof),
                (AS3 void*)(Bs + c * 8), 16, 0, 0);
        }
        __syncthreads();                        // drains vmcnt(0) (m97 pattern)
#pragma unroll
        for (int kk = 0; kk < 2; ++kk) {
            bf16x8 af[4], bfv[4];
#pragma unroll
            for (int mi = 0; mi < 4; ++mi) {
                int row = wr * 64 + mi * 16 + l15;
                af[mi] = *(const bf16x8*)(Ab + ((row * 128 + kk * 64 + lk * 16) ^ ((row & 7) << 4)));
            }
#pragma unroll
            for (int ni = 0; ni < 4; ++ni) {
                int row = wc * 64 + ni * 16 + l15;
                bfv[ni] = *(const bf16x8*)(Bb + ((row * 128 + kk * 64 + lk * 16) ^ ((row & 7) << 4)));
            }
#pragma unroll
            for (int mi = 0; mi < 4; ++mi)
#pragma unroll
                for (int ni = 0; ni < 4; ++ni)
                    acc[mi][ni] = MFMA16(af[mi], bfv[ni], acc[mi][ni]);
        }
    }

    // ---- epilogue: repack C-tile via LDS, store coalesced -----------------
    const int proj = bn >> 10;                  // uniform per block
    const int b = bm >> 11;
    const int bh = b * 8 + ((bn & 1023) >> 7);
    const int tbase = bm & 2047;

    __syncthreads();                            // staging reads done
    if (proj == 2) {
        // V: LDS T[dl][tl] (transpose), pack r-pairs (consecutive tl)
#pragma unroll
        for (int mi = 0; mi < 4; ++mi) {
#pragma unroll
            for (int ni = 0; ni < 4; ++ni) {
                int dl = wc * 64 + ni * 16 + l15;
                int tlb = wr * 64 + mi * 16 + lk * 4;
                int byte0 = (dl * 256 + tlb * 2) ^ ((dl & 7) << 4);
                *(uint32_t*)(Sb + byte0)     = pack_bf16(acc[mi][ni][0], acc[mi][ni][1]);
                *(uint32_t*)(Sb + byte0 + 4) = pack_bf16(acc[mi][ni][2], acc[mi][ni][3]);
            }
        }
    } else {
        // K/Q: LDS T[tl][dl]
#pragma unroll
        for (int mi = 0; mi < 4; ++mi) {
#pragma unroll
            for (int ni = 0; ni < 4; ++ni) {
                int dl = wc * 64 + ni * 16 + l15;
#pragma unroll
                for (int r = 0; r < 4; ++r) {
                    int tl = wr * 64 + mi * 16 + lk * 4 + r;
                    *(short*)(Sb + ((tl * 256 + dl * 2) ^ ((tl & 7) << 4))) = f2bf(acc[mi][ni][r]);
                }
            }
        }
    }
    __syncthreads();

    short* dst;
    if (proj == 2)
        dst = qkv + (size_t)2 * (32 * 2048 * 128) + (size_t)bh * 128 * 2048;
    else
        dst = qkv + (size_t)proj * (32 * 2048 * 128) + (size_t)bh * 2048 * 128;

#pragma unroll
    for (int i = 0; i < 8; ++i) {
        int c = i * 256 + tid;                  // 0..2047 16B chunks
        int row = c >> 4;
        uint4 v = *(const uint4*)(Sb + row * 256 + (((c & 15) * 16) ^ ((row & 7) << 4)));
        if (proj == 2) {
            // row = d, cols = t
            *(uint4*)(dst + (size_t)row * 2048 + tbase + (c & 15) * 8) = v;
        } else {
            // row = t, cols = d
            *(uint4*)(dst + (size_t)(tbase + row) * 128 + (c & 15) * 8) = v;
        }
    }
}

// ---------------------------------------------------------------------------
// Kernel 3: causal flash attention — split-phase counted-vmcnt pipeline.
// R2 post-mortem: parity waves idled half the block per tile and doubled
// barrier count -> MfmaUtil 14%. R0/R1 shared the real bottleneck: the
// staged-tile wait covers no compute (issue and wait adjacent), so each
// iteration pays load_completion + compute IN SERIES (~2.5-4.6k cyc/iter).
// This version:
//   - 512-thread blocks (8 waves = 4 q-chunks x 2 kv-halves), 128 q rows ->
//     8704 block-iters total (R0's staging volume, 278 MB), dense waves.
//   - K and V staged as separate vmcnt groups: issue K[j+1] at iter start,
//     wait vmcnt(4) for K[j] (cover = 1 full iteration); issue V[j+1] after
//     QK, wait vmcnt(4) for V[j] after softmax. Loads complete UNDER compute.
//     Only the last tile drains to 0.
//   - Frag-major conflict-free LDS (from R2, verified correct).
//   - Complementary pairing: blocks i and i+256 (same CU under round-robin)
//     get strips 15-k and k of the SAME bh -> 36 iters/CU uniform, 4 bh/XCD
//     (KV working set 4 MB = one XCD L2).
//   - End-of-block flash combine merges kv-halves (R1's verified code).
// Dynamic LDS 67584 B: K0 16K | K1 16K | V0 16K | V1 16K | (reused: combine
// ex 64K + ml 2K). 2 blocks/CU (135 KB of 160 KB).
// ---------------------------------------------------------------------------
__device__ inline void stage_K(const short* __restrict__ Kp, int j0,
                               char* smem, int buf)
{
    short* kls = (short*)(smem + (buf << 14));
    const int tid = threadIdx.x;               // 512 threads
#pragma unroll
    for (int i = 0; i < 2; ++i) {
        int c = i * 512 + tid;                 // 0..1023 16B chunks
        int slot = c >> 6, t = c & 63;         // slot = dblk*2+hh
        __builtin_amdgcn_global_load_lds(
            (const AS1 void*)(Kp + (size_t)(j0 + t) * 128 + slot * 8),
            (AS3 void*)(kls + c * 8), 16, 0, 0);
    }
}
__device__ inline void stage_V(const short* __restrict__ Vp, int j0,
                               char* smem, int buf)
{
    short* vls = (short*)(smem + 32768 + (buf << 14));
    const int tid = threadIdx.x;
#pragma unroll
    for (int i = 0; i < 2; ++i) {
        int c = i * 512 + tid;                 // 0..1023 16B chunks
        int slot = c >> 7, d = c & 127;        // slot = kv-octet index 0..7
        __builtin_amdgcn_global_load_lds(
            (const AS1 void*)(Vp + (size_t)d * 2048 + j0 + slot * 8),
            (AS3 void*)(vls + c * 8), 16, 0, 0);
    }
}

__global__ __launch_bounds__(512, 4)
void attn_kernel(const short* __restrict__ qkv, float* __restrict__ out)
{
    extern __shared__ char smem[];
    const int tid = threadIdx.x, lane = tid & 63, wave = tid >> 6;
    const int l31 = lane & 31;
    const int hh_ = lane >> 5;

    // complementary pairing: blocks i and i+256 land on the same CU under
    // round-robin (i%8 = XCD, (i/8)%32 = CU slot); give them strips 15-k and
    // k of the same bh -> uniform 36 iters/CU; 4 bh per XCD (~4MB KV = L2).
    const int i = blockIdx.x;
    const int bh = i & 31;
    const int kk_ = (i >> 5) & 7;
    const int sp = (i < 256) ? (15 - kk_) : kk_;
    const int q0 = sp * 128;

    const int qc = wave & 3;                    // q sub-block (32 rows)
    const int kvh = wave >> 2;                  // kv half of staged 64-kv tile

    const size_t HSTRIDE = (size_t)2048 * 128;
    const short* Kp = qkv + (size_t)bh * HSTRIDE;                    // [t][d]
    const short* Qp = qkv + (size_t)32 * HSTRIDE + (size_t)bh * HSTRIDE;
    const short* Vp = qkv + (size_t)64 * HSTRIDE + (size_t)bh * HSTRIDE; // [d][t]

    // Q B-operand frags: lane holds Q[q0+qc*32+l31][dblk*16 + hh_*8 + j]
    bf16x8 qf[8];
    {
        const short* qrow = Qp + (size_t)(q0 + qc * 32 + l31) * 128 + hh_ * 8;
#pragma unroll
        for (int dblk = 0; dblk < 8; ++dblk)
            qf[dblk] = *(const bf16x8*)(qrow + dblk * 16);
    }

    // per-lane softmax state for q = l31 (dup across halves), exp2 domain
    float mrow = -1e30f, lrow = 0.f;
    f32x16 acco[4] = {};                        // O[q(reg)][dt*32 + l31]

    const int nt = 2 * sp + 2;                  // 64-kv tiles
    const int qwave = q0 + qc * 32;
    const int qglob = qwave + l31;

    // prologue: K0, V0 into buffer 0 (4 loads/thread outstanding)
    stage_K(Kp, 0, smem, 0);
    stage_V(Vp, 0, smem, 0);

    for (int jt = 0; jt < nt; ++jt) {
        const int j0 = jt << 6;
        const int nb = (jt + 1) & 1;
        const bool pre = (jt + 1 < nt);

        // ---- K phase: issue next K, wait current K --------------------
        if (pre) stage_K(Kp + (size_t)64 * 128, Kp == Kp ? (jt + 1) << 6 : 0, smem, nb);
        if (pre) { asm volatile("s_waitcnt vmcnt(4)" ::: "memory"); }
        else     { asm volatile("s_waitcnt vmcnt(2)" ::: "memory"); }
        __builtin_amdgcn_sched_barrier(0);
        __builtin_amdgcn_s_barrier();           // K[j] visible to all waves
        __builtin_amdgcn_sched_barrier(0);

        const int kv0 = j0 + kvh * 32;          // this wave's 32-kv window
        const bool act = (kv0 <= qwave + 31);   // wave-uniform causal gate

        const short* kls = (const short*)(smem + ((jt & 1) << 14));
        const short* vls = (const short*)(smem + 32768 + ((jt & 1) << 14));

        f32x16 sacc = {};
        if (act) {
            // S'^T = K Q'^T : lane pair (l, l^32) holds S'[kv 0..31][q=l31]
            __builtin_amdgcn_s_setprio(1);
#pragma unroll
            for (int dblk = 0; dblk < 8; ++dblk) {
                bf16x8 kf = *(const bf16x8*)(kls + ((dblk * 2 + hh_) * 64 + kvh * 32 + l31) * 8);
                sacc = MFMA32(kf, qf[dblk], sacc);
            }
            __builtin_amdgcn_s_setprio(0);
        }

        // ---- V phase: issue next V under softmax ----------------------
        if (pre) stage_V(Vp, (jt + 1) << 6, smem, nb);

        float psum = 0.f;
        uint32_t pkA[4], pkB[4];
        if (act) {
            // causal mask: only the straddle window
            if (kv0 + 31 > qwave) {
#pragma unroll
                for (int r = 0; r < 16; ++r) {
                    int kvglob = kv0 + (r & 3) + 8 * (r >> 2) + 4 * hh_;
                    if (kvglob > qglob) sacc[r] = -1e30f;
                }
            }

            // row max: in-lane tree + 1 cross-half shuffle
            float pmax = -1e30f;
#pragma unroll
            for (int r = 0; r < 16; r += 4) {
                float a = fmaxf(sacc[r], sacc[r + 1]);
                float b2 = fmaxf(sacc[r + 2], sacc[r + 3]);
                pmax = fmaxf(pmax, fmaxf(a, b2));
            }
            pmax = fmaxf(pmax, __shfl_xor(pmax, 32));

            // defer-max: rescale only when max grew by > 8 nats (11.54 bits)
            if (!__all(pmax - mrow <= 11.5416f)) {
                float mn = fmaxf(mrow, pmax);
                float alpha = __builtin_amdgcn_exp2f(mrow - mn);
                mrow = mn;
                lrow *= alpha;
#pragma unroll
                for (int r = 0; r < 16; ++r) {
                    float ar = __shfl(alpha, (r & 3) + 8 * (r >> 2) + 4 * hh_);
#pragma unroll
                    for (int dt = 0; dt < 4; ++dt) acco[dt][r] *= ar;
                }
            }

            // P = exp2(S' - m'), row sum, pack to bf16 pairs
#pragma unroll
            for (int sg = 0; sg < 4; ++sg) {
                float p0 = __builtin_amdgcn_exp2f(sacc[4 * sg + 0] - mrow);
                float p1 = __builtin_amdgcn_exp2f(sacc[4 * sg + 1] - mrow);
                float p2 = __builtin_amdgcn_exp2f(sacc[4 * sg + 2] - mrow);
                float p3 = __builtin_amdgcn_exp2f(sacc[4 * sg + 3] - mrow);
                psum += (p0 + p1) + (p2 + p3);
                pkA[sg] = pack_bf16(p0, p1);
                pkB[sg] = pack_bf16(p2, p3);
            }
            psum += __shfl_xor(psum, 32);
            lrow += psum;
        }

        if (pre) { asm volatile("s_waitcnt vmcnt(4)" ::: "memory"); }
        else     { asm volatile("s_waitcnt vmcnt(0)" ::: "memory"); }
        __builtin_amdgcn_sched_barrier(0);
        __builtin_amdgcn_s_barrier();           // V[j] visible to all waves
        __builtin_amdgcn_sched_barrier(0);

        if (act) {
            // O += P V  (P A-frags assembled in-register via cross-half swaps)
            __builtin_amdgcn_s_setprio(1);
#pragma unroll
            for (int kb = 0; kb < 2; ++kb) {
                uint32_t r0, r1, r2, r3;
                SWAP32(r0, r2, pkA[2 * kb], pkA[2 * kb + 1]);
                SWAP32(r1, r3, pkB[2 * kb], pkB[2 * kb + 1]);
                union { uint32_t u[4]; bf16x8 v; } pa;
                pa.u[0] = r0; pa.u[1] = r1; pa.u[2] = r2; pa.u[3] = r3;
                const int slot = kvh * 4 + kb * 2 + hh_;   // kv octet in tile
#pragma unroll
                for (int dt = 0; dt < 4; ++dt) {
                    bf16x8 vf = *(const bf16x8*)(vls + (slot * 128 + dt * 32 + l31) * 8);
                    acco[dt] = MFMA32(pa.v, vf, acco[dt]);
                }
            }
            __builtin_amdgcn_s_setprio(0);
        }
    }

    // ---- intra-block flash combine: merge kv halves (waves w and w+4) -----
    __syncthreads();                            // all waves done reading LDS
    float* ex = (float*)smem;                   // 4 chunks x 4096 f32 (64 KB)
    float* ml = (float*)(smem + 65536);         // 4 chunks x 64 x {m,l} (2 KB)
    if (kvh == 1) {
        float* dst = ex + qc * 4096;
#pragma unroll
        for (int dt = 0; dt < 4; ++dt)
#pragma unroll
            for (int r = 0; r < 16; ++r)
                dst[(dt * 16 + r) * 64 + lane] = acco[dt][r];
        ml[qc * 128 + lane * 2 + 0] = mrow;
        ml[qc * 128 + lane * 2 + 1] = lrow;
    }
    __syncthreads();
    if (kvh == 0) {
        float m1 = ml[qc * 128 + lane * 2 + 0];
        float l1 = ml[qc * 128 + lane * 2 + 1];
        float M  = fmaxf(mrow, m1);
        float a  = __builtin_amdgcn_exp2f(mrow - M);
        float b2 = __builtin_amdgcn_exp2f(m1 - M);   // 0 if half had no work
        float lf = lrow * a + l1 * b2;
        float sA = a / lf, sB = b2 / lf;
        const float* src = ex + qc * 4096;
        const int b = bh >> 3, hd = bh & 7;
#pragma unroll
        for (int r = 0; r < 16; ++r) {
            int ql = (r & 3) + 8 * (r >> 2) + 4 * hh_;
            float sa = __shfl(sA, ql);
            float sb = __shfl(sB, ql);
            int t = qwave + ql;
            float* o = out + (size_t)(b * 2048 + t) * 1024 + hd * 128 + l31;
#pragma unroll
            for (int dt = 0; dt < 4; ++dt)
                o[dt * 32] = acco[dt][r] * sa + src[(dt * 16 + r) * 64 + lane] * sb;
        }
    }
}

// ---------------------------------------------------------------------------
extern "C" void kernel_launch(void* const* d_in, const int* in_sizes, int n_in,
                              void* d_out, int out_size, void* d_ws, size_t ws_size,
                              hipStream_t stream) {
    const float* x  = (const float*)d_in[0];
    const float* w  = (const float*)d_in[1];
    const float* bK = (const float*)d_in[2];
    const float* bQ = (const float*)d_in[3];
    const float* bV = (const float*)d_in[4];

    // workspace layout (bytes): xb 8,388,608 | W 3,145,728 | qkv 50,331,648
    short* xb  = (short*)d_ws;
    short* W   = (short*)((char*)d_ws + 8388608);
    short* qkv = (short*)((char*)d_ws + 8388608 + 3145728);
    float* out = (float*)d_out;

    // allow 66 KB dynamic LDS (idempotent; not a stream op, capture-safe)
    hipFuncSetAttribute((const void*)attn_kernel,
                        hipFuncAttributeMaxDynamicSharedMemorySize, 67584);

    prep_kernel<<<2048, 256, 0, stream>>>(x, w, bK, bQ, bV, xb, W);
    proj_gemm<<<64 * 24, 256, 0, stream>>>(xb, W, qkv);
    attn_kernel<<<512, 512, 67584, stream>>>(qkv, out);
}

// Round 4
// 110.595 us; speedup vs baseline: 2.0338x; 2.0338x over previous
//
#include <hip/hip_runtime.h>
#include <hip/hip_bf16.h>
#include <stdint.h>

typedef __attribute__((ext_vector_type(8))) short bf16x8;
typedef __attribute__((ext_vector_type(4))) float f32x4;
typedef __attribute__((ext_vector_type(16))) float f32x16;

#define MFMA16(a,b,c) __builtin_amdgcn_mfma_f32_16x16x32_bf16((a),(b),(c),0,0,0)
#define MFMA32(a,b,c) __builtin_amdgcn_mfma_f32_32x32x16_bf16((a),(b),(c),0,0,0)
#define AS1 __attribute__((address_space(1)))
#define AS3 __attribute__((address_space(3)))

__device__ inline short f2bf(float f) {
    union { __hip_bfloat16 h; short s; } u;
    u.h = __float2bfloat16(f);
    return u.s;
}
__device__ inline uint32_t pack_bf16(float a, float b) {
    union { __hip_bfloat16 h; uint16_t u; } ua, ub;
    ua.h = __float2bfloat16(a); ub.h = __float2bfloat16(b);
    return (uint32_t)ua.u | ((uint32_t)ub.u << 16);
}

// cross-half register exchange
#if __has_builtin(__builtin_amdgcn_permlane32_swap)
#define SWAP32(x, y, a, b) { auto _r = __builtin_amdgcn_permlane32_swap((a),(b),false,false); \
                             (x) = _r[0]; (y) = _r[1]; }
#else
#define SWAP32(x, y, a, b) { uint32_t _ta = __shfl_xor((uint32_t)(a),32); \
                             uint32_t _tb = __shfl_xor((uint32_t)(b),32); \
                             (x) = hh_ ? _tb : (a); (y) = hh_ ? (b) : _ta; }
#endif

// S' = S * scale * log2(e): fold into Wq so attention exp is native exp2.
#define QSCALE 0.12751879523879295f   // (1/sqrt(128)) * log2(e)

// ---------------------------------------------------------------------------
// Kernel 1: eff-weight mix -> bf16 W [3][8][128][512]; x f32 -> bf16
// ---------------------------------------------------------------------------
#define NW (8*128*512)        // 524288 per projection
#define NX4 (8192*512/4)      // 1048576 float4 chunks of x

__global__ void prep_kernel(const float* __restrict__ x,
                            const float* __restrict__ w,
                            const float* __restrict__ bK,
                            const float* __restrict__ bQ,
                            const float* __restrict__ bV,
                            short* __restrict__ xb,    // [8192][512]
                            short* __restrict__ W)     // [3][1024][512]  (K,Q,V)
{
    const float w0 = w[0], w1 = w[1], w2 = w[2], w3 = w[3];
    for (int i = blockIdx.x * blockDim.x + threadIdx.x; i < NW + NX4;
         i += gridDim.x * blockDim.x) {
        if (i < NW) {
            int e = i & 511;
            int d = (i >> 9) & 127;
            int h = i >> 16;
            float eff = 0.f;
            if (h < 4) { eff += w2; if (d < 64 && e < 256) eff += w0; }
            if (d < 32 && e < 256) eff += w1;
            if (d < 64) eff += w3;
            W[i]          = f2bf(eff * bK[i]);
            W[i + NW]     = f2bf(eff * bQ[i] * QSCALE);
            W[i + 2*NW]   = f2bf(eff * bV[i]);
        } else {
            int j = i - NW;
            float4 v = ((const float4*)x)[j];
            short4 o;
            o.x = f2bf(v.x); o.y = f2bf(v.y); o.z = f2bf(v.z); o.w = f2bf(v.w);
            ((short4*)xb)[j] = o;
        }
    }
}

// ---------------------------------------------------------------------------
// Kernel 2: C[8192,3072] = xb[8192,512] @ W[3072,512]^T
// K,Q stored [bh][t][d]; V stored TRANSPOSED as [bh][d][t].
// LDS-repacked coalesced epilogue; bijective XCD grid swizzle.
// ---------------------------------------------------------------------------
__global__ __launch_bounds__(256)
void proj_gemm(const short* __restrict__ A,    // [8192][512]
               const short* __restrict__ Bw,   // [3072][512]
               short* __restrict__ qkv)
{
    __shared__ short S[128 * 128];             // 32 KB: staging + repack
    short* As = S;                             // 16 KB
    short* Bs = S + 128 * 64;                  // 16 KB
    const int tid = threadIdx.x;
    const int lane = tid & 63;
    const int wave = tid >> 6;
    const int wr = wave >> 1, wc = wave & 1;
    const int l15 = lane & 15, lk = lane >> 4;

    // bijective XCD swizzle: 1536 blocks, 192 consecutive per XCD
    const int wg = (blockIdx.x & 7) * 192 + (blockIdx.x >> 3);
    const int bm = (wg / 24) * 128;
    const int bn = (wg % 24) * 128;

    char* Ab = (char*)As;
    char* Bb = (char*)Bs;
    char* Sb = (char*)S;
    f32x4 acc[4][4] = {};

    for (int k0 = 0; k0 < 512; k0 += 64) {
        __syncthreads();
#pragma unroll
        for (int i = 0; i < 4; ++i) {
            int c = i * 256 + tid;              // 0..1023, 16B chunk
            int lin = c * 16;                   // linear byte in 16 KB tile
            int row = lin >> 7;                 // 0..127
            int cof = ((lin & 127) ^ ((row & 7) << 4)) >> 1;   // shorts
            __builtin_amdgcn_global_load_lds(
                (const AS1 void*)(A + (size_t)(bm + row) * 512 + k0 + cof),
                (AS3 void*)(As + c * 8), 16, 0, 0);
            __builtin_amdgcn_global_load_lds(
                (const AS1 void*)(Bw + (size_t)(bn + row) * 512 + k0 + cof),
                (AS3 void*)(Bs + c * 8), 16, 0, 0);
        }
        __syncthreads();                        // drains vmcnt(0) (m97 pattern)
#pragma unroll
        for (int kk = 0; kk < 2; ++kk) {
            bf16x8 af[4], bfv[4];
#pragma unroll
            for (int mi = 0; mi < 4; ++mi) {
                int row = wr * 64 + mi * 16 + l15;
                af[mi] = *(const bf16x8*)(Ab + ((row * 128 + kk * 64 + lk * 16) ^ ((row & 7) << 4)));
            }
#pragma unroll
            for (int ni = 0; ni < 4; ++ni) {
                int row = wc * 64 + ni * 16 + l15;
                bfv[ni] = *(const bf16x8*)(Bb + ((row * 128 + kk * 64 + lk * 16) ^ ((row & 7) << 4)));
            }
#pragma unroll
            for (int mi = 0; mi < 4; ++mi)
#pragma unroll
                for (int ni = 0; ni < 4; ++ni)
                    acc[mi][ni] = MFMA16(af[mi], bfv[ni], acc[mi][ni]);
        }
    }

    // ---- epilogue: repack C-tile via LDS, store coalesced -----------------
    const int proj = bn >> 10;                  // uniform per block
    const int b = bm >> 11;
    const int bh = b * 8 + ((bn & 1023) >> 7);
    const int tbase = bm & 2047;

    __syncthreads();                            // staging reads done
    if (proj == 2) {
        // V: LDS T[dl][tl] (transpose), pack r-pairs (consecutive tl)
#pragma unroll
        for (int mi = 0; mi < 4; ++mi) {
#pragma unroll
            for (int ni = 0; ni < 4; ++ni) {
                int dl = wc * 64 + ni * 16 + l15;
                int tlb = wr * 64 + mi * 16 + lk * 4;
                int byte0 = (dl * 256 + tlb * 2) ^ ((dl & 7) << 4);
                *(uint32_t*)(Sb + byte0)     = pack_bf16(acc[mi][ni][0], acc[mi][ni][1]);
                *(uint32_t*)(Sb + byte0 + 4) = pack_bf16(acc[mi][ni][2], acc[mi][ni][3]);
            }
        }
    } else {
        // K/Q: LDS T[tl][dl]
#pragma unroll
        for (int mi = 0; mi < 4; ++mi) {
#pragma unroll
            for (int ni = 0; ni < 4; ++ni) {
                int dl = wc * 64 + ni * 16 + l15;
#pragma unroll
                for (int r = 0; r < 4; ++r) {
                    int tl = wr * 64 + mi * 16 + lk * 4 + r;
                    *(short*)(Sb + ((tl * 256 + dl * 2) ^ ((tl & 7) << 4))) = f2bf(acc[mi][ni][r]);
                }
            }
        }
    }
    __syncthreads();

    short* dst;
    if (proj == 2)
        dst = qkv + (size_t)2 * (32 * 2048 * 128) + (size_t)bh * 128 * 2048;
    else
        dst = qkv + (size_t)proj * (32 * 2048 * 128) + (size_t)bh * 2048 * 128;

#pragma unroll
    for (int i = 0; i < 8; ++i) {
        int c = i * 256 + tid;                  // 0..2047 16B chunks
        int row = c >> 4;
        uint4 v = *(const uint4*)(Sb + row * 256 + (((c & 15) * 16) ^ ((row & 7) << 4)));
        if (proj == 2) {
            // row = d, cols = t
            *(uint4*)(dst + (size_t)row * 2048 + tbase + (c & 15) * 8) = v;
        } else {
            // row = t, cols = d
            *(uint4*)(dst + (size_t)(tbase + row) * 128 + (c & 15) * 8) = v;
        }
    }
}

// ---------------------------------------------------------------------------
// Kernel 3: causal flash attention — uniform-duration 8-wave blocks.
// R0-R3 consolidated: per-iteration latency ~4.6k cyc is hidden only when 2+
// waves/SIMD are resident; R0's (short,long) pairing left CUs SOLO ~half the
// time (occupancy 12.5%). Fix: 256 blocks x 512 threads; block (bh,a) runs
// q-strip a (2a+2 tiles) then strip 15-a (32-2a tiles) -> EVERY block = 36
// iterations of 128q x 64kv. 1 block/CU, 8 waves = 2/SIMD for the whole
// kernel; zero tail. bh%8 = XCD -> 4 heads/XCD (4 MB KV = L2).
// Waves = 4 q-chunks x 2 kv-halves (all dense, 8+8 MFMA32 each); per-half
// online softmax; R1-verified LDS flash-combine at each strip end.
// Staging: R0's verified issue-then-wait double buffer, 4 loads/thread/tile,
// steady vmcnt(4) (one full iteration of cover); frag-major conflict-free LDS.
// Dynamic LDS 67584 B: dbuf 2 x {K 16K | V 16K} (0..64K); combine aliases it
// (ex 64K @0, ml 2K @64K) with barriers separating the phases.
// ---------------------------------------------------------------------------
__device__ inline void stage64(const short* __restrict__ Kp,
                               const short* __restrict__ Vp,
                               int j0, char* smem, int buf)
{
    short* kls = (short*)(smem + (buf << 15));   // 32 KB per buffer
    short* vls = kls + 8192;                     // +16 KB (shorts)
    const int tid = threadIdx.x;                 // 512 threads
    // K tile frag-major: chunk c = slot*64 + t, slot = dblk*2+hh (0..15)
#pragma unroll
    for (int i = 0; i < 2; ++i) {
        int c = i * 512 + tid;                   // 0..1023
        int slot = c >> 6, t = c & 63;
        __builtin_amdgcn_global_load_lds(
            (const AS1 void*)(Kp + (size_t)(j0 + t) * 128 + slot * 8),
            (AS3 void*)(kls + c * 8), 16, 0, 0);
    }
    // V tile frag-major: chunk c = slot*128 + d, slot = kv-octet (0..7)
#pragma unroll
    for (int i = 0; i < 2; ++i) {
        int c = i * 512 + tid;                   // 0..1023
        int slot = c >> 7, d = c & 127;
        __builtin_amdgcn_global_load_lds(
            (const AS1 void*)(Vp + (size_t)d * 2048 + j0 + slot * 8),
            (AS3 void*)(vls + c * 8), 16, 0, 0);
    }
}

__global__ __launch_bounds__(512, 2)
void attn_kernel(const short* __restrict__ qkv, float* __restrict__ out)
{
    extern __shared__ char smem[];
    const int tid = threadIdx.x, lane = tid & 63, wave = tid >> 6;
    const int l31 = lane & 31;
    const int hh_ = lane >> 5;

    const int bh = blockIdx.x & 31;             // bh%8 = XCD under round-robin
    const int a = blockIdx.x >> 5;              // 0..7

    const int qc = wave & 3;                    // q sub-block (32 rows)
    const int kvh = wave >> 2;                  // kv half of staged 64-kv tile

    const size_t HSTRIDE = (size_t)2048 * 128;
    const short* Kp = qkv + (size_t)bh * HSTRIDE;                    // [t][d]
    const short* Qp = qkv + (size_t)32 * HSTRIDE + (size_t)bh * HSTRIDE;
    const short* Vp = qkv + (size_t)64 * HSTRIDE + (size_t)bh * HSTRIDE; // [d][t]

    for (int sidx = 0; sidx < 2; ++sidx) {
        const int sp = sidx ? (15 - a) : a;     // strip index 0..15
        const int q0 = sp * 128;
        const int nt = 2 * sp + 2;              // 64-kv tiles
        const int qwave = q0 + qc * 32;
        const int qglob = qwave + l31;

        __syncthreads();                        // LDS free (prev combine done)

        // Q B-operand frags (issued before staging; drained by first vmcnt)
        bf16x8 qf[8];
        {
            const short* qrow = Qp + (size_t)(q0 + qc * 32 + l31) * 128 + hh_ * 8;
#pragma unroll
            for (int dblk = 0; dblk < 8; ++dblk)
                qf[dblk] = *(const bf16x8*)(qrow + dblk * 16);
        }

        float mrow = -1e30f, lrow = 0.f;
        f32x16 acco[4] = {};                    // O[q(reg)][dt*32 + l31]

        stage64(Kp, Vp, 0, smem, 0);            // prologue: tile 0 -> buf 0

        for (int jt = 0; jt < nt; ++jt) {
            const int j0 = jt << 6;
            __builtin_amdgcn_s_barrier();       // all waves done with buf jt^1
            if (jt + 1 < nt) {
                stage64(Kp, Vp, (jt + 1) << 6, smem, (jt + 1) & 1);
                asm volatile("s_waitcnt vmcnt(4)" ::: "memory");  // tile jt done
            } else {
                asm volatile("s_waitcnt vmcnt(0)" ::: "memory");
            }
            __builtin_amdgcn_sched_barrier(0);
            __builtin_amdgcn_s_barrier();       // tile jt visible to all waves
            __builtin_amdgcn_sched_barrier(0);

            const int kv0 = j0 + kvh * 32;      // this wave's 32-kv window
            if (kv0 <= qwave + 31) {            // wave-uniform causal gate
                const short* kls = (const short*)(smem + ((jt & 1) << 15));
                const short* vls = kls + 8192;

                // S'^T = K Q'^T : lane pair (l, l^32) holds S'[kv][q=l31]
                f32x16 sacc = {};
                __builtin_amdgcn_s_setprio(1);
#pragma unroll
                for (int dblk = 0; dblk < 8; ++dblk) {
                    bf16x8 kf = *(const bf16x8*)(kls + ((dblk * 2 + hh_) * 64 + kvh * 32 + l31) * 8);
                    sacc = MFMA32(kf, qf[dblk], sacc);
                }
                __builtin_amdgcn_s_setprio(0);

                // causal mask: only the straddle window (kv0 == qwave)
                if (kv0 + 31 > qwave) {
#pragma unroll
                    for (int r = 0; r < 16; ++r) {
                        int kvglob = kv0 + (r & 3) + 8 * (r >> 2) + 4 * hh_;
                        if (kvglob > qglob) sacc[r] = -1e30f;
                    }
                }

                // row max: in-lane tree + 1 cross-half shuffle
                float pmax = -1e30f;
#pragma unroll
                for (int r = 0; r < 16; r += 4) {
                    float a2 = fmaxf(sacc[r], sacc[r + 1]);
                    float b2 = fmaxf(sacc[r + 2], sacc[r + 3]);
                    pmax = fmaxf(pmax, fmaxf(a2, b2));
                }
                pmax = fmaxf(pmax, __shfl_xor(pmax, 32));

                // defer-max: rescale only when max grew by > 8 nats
                if (!__all(pmax - mrow <= 11.5416f)) {
                    float mn = fmaxf(mrow, pmax);
                    float alpha = __builtin_amdgcn_exp2f(mrow - mn);
                    mrow = mn;
                    lrow *= alpha;
#pragma unroll
                    for (int r = 0; r < 16; ++r) {
                        float ar = __shfl(alpha, (r & 3) + 8 * (r >> 2) + 4 * hh_);
#pragma unroll
                        for (int dt = 0; dt < 4; ++dt) acco[dt][r] *= ar;
                    }
                }

                // P = exp2(S' - m'), row sum, pack to bf16 pairs
                float psum = 0.f;
                uint32_t pkA[4], pkB[4];
#pragma unroll
                for (int sg = 0; sg < 4; ++sg) {
                    float p0 = __builtin_amdgcn_exp2f(sacc[4 * sg + 0] - mrow);
                    float p1 = __builtin_amdgcn_exp2f(sacc[4 * sg + 1] - mrow);
                    float p2 = __builtin_amdgcn_exp2f(sacc[4 * sg + 2] - mrow);
                    float p3 = __builtin_amdgcn_exp2f(sacc[4 * sg + 3] - mrow);
                    psum += (p0 + p1) + (p2 + p3);
                    pkA[sg] = pack_bf16(p0, p1);
                    pkB[sg] = pack_bf16(p2, p3);
                }
                psum += __shfl_xor(psum, 32);
                lrow += psum;

                // O += P V  (P A-frags assembled via cross-half swaps)
                __builtin_amdgcn_s_setprio(1);
#pragma unroll
                for (int kb = 0; kb < 2; ++kb) {
                    uint32_t r0, r1, r2, r3;
                    SWAP32(r0, r2, pkA[2 * kb], pkA[2 * kb + 1]);
                    SWAP32(r1, r3, pkB[2 * kb], pkB[2 * kb + 1]);
                    union { uint32_t u[4]; bf16x8 v; } pa;
                    pa.u[0] = r0; pa.u[1] = r1; pa.u[2] = r2; pa.u[3] = r3;
                    const int slot = kvh * 4 + kb * 2 + hh_;   // kv octet
#pragma unroll
                    for (int dt = 0; dt < 4; ++dt) {
                        bf16x8 vf = *(const bf16x8*)(vls + (slot * 128 + dt * 32 + l31) * 8);
                        acco[dt] = MFMA32(pa.v, vf, acco[dt]);
                    }
                }
                __builtin_amdgcn_s_setprio(0);
            }
        }

        // ---- intra-block flash combine: merge kv halves (waves w, w+4) ----
        __syncthreads();                        // all waves done reading LDS
        float* ex = (float*)smem;               // 4 chunks x 4096 f32 (64 KB)
        float* ml = (float*)(smem + 65536);     // 4 chunks x 64 x {m,l} (2 KB)
        if (kvh == 1) {
            float* dst = ex + qc * 4096;
#pragma unroll
            for (int dt = 0; dt < 4; ++dt)
#pragma unroll
                for (int r = 0; r < 16; ++r)
                    dst[(dt * 16 + r) * 64 + lane] = acco[dt][r];
            ml[qc * 128 + lane * 2 + 0] = mrow;
            ml[qc * 128 + lane * 2 + 1] = lrow;
        }
        __syncthreads();
        if (kvh == 0) {
            float m1 = ml[qc * 128 + lane * 2 + 0];
            float l1 = ml[qc * 128 + lane * 2 + 1];
            float M  = fmaxf(mrow, m1);
            float av = __builtin_amdgcn_exp2f(mrow - M);
            float bv = __builtin_amdgcn_exp2f(m1 - M);  // 0 if half empty
            float lf = lrow * av + l1 * bv;
            float sA = av / lf, sB = bv / lf;
            const float* src = ex + qc * 4096;
            const int bb = bh >> 3, hd = bh & 7;
#pragma unroll
            for (int r = 0; r < 16; ++r) {
                int ql = (r & 3) + 8 * (r >> 2) + 4 * hh_;
                float sa = __shfl(sA, ql);
                float sb = __shfl(sB, ql);
                int t = qwave + ql;
                float* o = out + (size_t)(bb * 2048 + t) * 1024 + hd * 128 + l31;
#pragma unroll
                for (int dt = 0; dt < 4; ++dt)
                    o[dt * 32] = acco[dt][r] * sa + src[(dt * 16 + r) * 64 + lane] * sb;
            }
        }
    }
}

// ---------------------------------------------------------------------------
extern "C" void kernel_launch(void* const* d_in, const int* in_sizes, int n_in,
                              void* d_out, int out_size, void* d_ws, size_t ws_size,
                              hipStream_t stream) {
    const float* x  = (const float*)d_in[0];
    const float* w  = (const float*)d_in[1];
    const float* bK = (const float*)d_in[2];
    const float* bQ = (const float*)d_in[3];
    const float* bV = (const float*)d_in[4];

    // workspace layout (bytes): xb 8,388,608 | W 3,145,728 | qkv 50,331,648
    short* xb  = (short*)d_ws;
    short* W   = (short*)((char*)d_ws + 8388608);
    short* qkv = (short*)((char*)d_ws + 8388608 + 3145728);
    float* out = (float*)d_out;

    // allow 66 KB dynamic LDS (idempotent; not a stream op, capture-safe)
    hipFuncSetAttribute((const void*)attn_kernel,
                        hipFuncAttributeMaxDynamicSharedMemorySize, 67584);

    prep_kernel<<<2048, 256, 0, stream>>>(x, w, bK, bQ, bV, xb, W);
    proj_gemm<<<64 * 24, 256, 0, stream>>>(xb, W, qkv);
    attn_kernel<<<256, 512, 67584, stream>>>(qkv, out);
}

// Round 5
// 107.853 us; speedup vs baseline: 2.0855x; 1.0254x over previous
//
#include <hip/hip_runtime.h>
#include <hip/hip_bf16.h>
#include <stdint.h>

typedef __attribute__((ext_vector_type(8))) short bf16x8;
typedef __attribute__((ext_vector_type(4))) float f32x4;
typedef __attribute__((ext_vector_type(16))) float f32x16;

#define MFMA16(a,b,c) __builtin_amdgcn_mfma_f32_16x16x32_bf16((a),(b),(c),0,0,0)
#define MFMA32(a,b,c) __builtin_amdgcn_mfma_f32_32x32x16_bf16((a),(b),(c),0,0,0)
#define AS1 __attribute__((address_space(1)))
#define AS3 __attribute__((address_space(3)))

__device__ inline short f2bf(float f) {
    union { __hip_bfloat16 h; short s; } u;
    u.h = __float2bfloat16(f);
    return u.s;
}
__device__ inline uint32_t pack_bf16(float a, float b) {
    union { __hip_bfloat16 h; uint16_t u; } ua, ub;
    ua.h = __float2bfloat16(a); ub.h = __float2bfloat16(b);
    return (uint32_t)ua.u | ((uint32_t)ub.u << 16);
}

// cross-half register exchange
#if __has_builtin(__builtin_amdgcn_permlane32_swap)
#define SWAP32(x, y, a, b) { auto _r = __builtin_amdgcn_permlane32_swap((a),(b),false,false); \
                             (x) = _r[0]; (y) = _r[1]; }
#else
#define SWAP32(x, y, a, b) { uint32_t _ta = __shfl_xor((uint32_t)(a),32); \
                             uint32_t _tb = __shfl_xor((uint32_t)(b),32); \
                             (x) = hh_ ? _tb : (a); (y) = hh_ ? (b) : _ta; }
#endif

// S' = S * scale * log2(e): fold into Wq so attention exp is native exp2.
#define QSCALE 0.12751879523879295f   // (1/sqrt(128)) * log2(e)

// ---------------------------------------------------------------------------
// Kernel 1: eff-weight mix -> bf16 W [3][8][128][512]; x f32 -> bf16
// ---------------------------------------------------------------------------
#define NW (8*128*512)        // 524288 per projection
#define NX4 (8192*512/4)      // 1048576 float4 chunks of x

__global__ void prep_kernel(const float* __restrict__ x,
                            const float* __restrict__ w,
                            const float* __restrict__ bK,
                            const float* __restrict__ bQ,
                            const float* __restrict__ bV,
                            short* __restrict__ xb,    // [8192][512]
                            short* __restrict__ W)     // [3][1024][512]  (K,Q,V)
{
    const float w0 = w[0], w1 = w[1], w2 = w[2], w3 = w[3];
    for (int i = blockIdx.x * blockDim.x + threadIdx.x; i < NW + NX4;
         i += gridDim.x * blockDim.x) {
        if (i < NW) {
            int e = i & 511;
            int d = (i >> 9) & 127;
            int h = i >> 16;
            float eff = 0.f;
            if (h < 4) { eff += w2; if (d < 64 && e < 256) eff += w0; }
            if (d < 32 && e < 256) eff += w1;
            if (d < 64) eff += w3;
            W[i]          = f2bf(eff * bK[i]);
            W[i + NW]     = f2bf(eff * bQ[i] * QSCALE);
            W[i + 2*NW]   = f2bf(eff * bV[i]);
        } else {
            int j = i - NW;
            float4 v = ((const float4*)x)[j];
            short4 o;
            o.x = f2bf(v.x); o.y = f2bf(v.y); o.z = f2bf(v.z); o.w = f2bf(v.w);
            ((short4*)xb)[j] = o;
        }
    }
}

// ---------------------------------------------------------------------------
// Kernel 2: C[8192,3072] = xb[8192,512] @ W[3072,512]^T
// K,Q stored [bh][t][d]; V stored TRANSPOSED as [bh][d][t].
// LDS-repacked coalesced epilogue; bijective XCD grid swizzle.
// ---------------------------------------------------------------------------
__global__ __launch_bounds__(256)
void proj_gemm(const short* __restrict__ A,    // [8192][512]
               const short* __restrict__ Bw,   // [3072][512]
               short* __restrict__ qkv)
{
    __shared__ short S[128 * 128];             // 32 KB: staging + repack
    short* As = S;                             // 16 KB
    short* Bs = S + 128 * 64;                  // 16 KB
    const int tid = threadIdx.x;
    const int lane = tid & 63;
    const int wave = tid >> 6;
    const int wr = wave >> 1, wc = wave & 1;
    const int l15 = lane & 15, lk = lane >> 4;

    // bijective XCD swizzle: 1536 blocks, 192 consecutive per XCD
    const int wg = (blockIdx.x & 7) * 192 + (blockIdx.x >> 3);
    const int bm = (wg / 24) * 128;
    const int bn = (wg % 24) * 128;

    char* Ab = (char*)As;
    char* Bb = (char*)Bs;
    char* Sb = (char*)S;
    f32x4 acc[4][4] = {};

    for (int k0 = 0; k0 < 512; k0 += 64) {
        __syncthreads();
#pragma unroll
        for (int i = 0; i < 4; ++i) {
            int c = i * 256 + tid;              // 0..1023, 16B chunk
            int lin = c * 16;                   // linear byte in 16 KB tile
            int row = lin >> 7;                 // 0..127
            int cof = ((lin & 127) ^ ((row & 7) << 4)) >> 1;   // shorts
            __builtin_amdgcn_global_load_lds(
                (const AS1 void*)(A + (size_t)(bm + row) * 512 + k0 + cof),
                (AS3 void*)(As + c * 8), 16, 0, 0);
            __builtin_amdgcn_global_load_lds(
                (const AS1 void*)(Bw + (size_t)(bn + row) * 512 + k0 + cof),
                (AS3 void*)(Bs + c * 8), 16, 0, 0);
        }
        __syncthreads();                        // drains vmcnt(0) (m97 pattern)
#pragma unroll
        for (int kk = 0; kk < 2; ++kk) {
            bf16x8 af[4], bfv[4];
#pragma unroll
            for (int mi = 0; mi < 4; ++mi) {
                int row = wr * 64 + mi * 16 + l15;
                af[mi] = *(const bf16x8*)(Ab + ((row * 128 + kk * 64 + lk * 16) ^ ((row & 7) << 4)));
            }
#pragma unroll
            for (int ni = 0; ni < 4; ++ni) {
                int row = wc * 64 + ni * 16 + l15;
                bfv[ni] = *(const bf16x8*)(Bb + ((row * 128 + kk * 64 + lk * 16) ^ ((row & 7) << 4)));
            }
#pragma unroll
            for (int mi = 0; mi < 4; ++mi)
#pragma unroll
                for (int ni = 0; ni < 4; ++ni)
                    acc[mi][ni] = MFMA16(af[mi], bfv[ni], acc[mi][ni]);
        }
    }

    // ---- epilogue: repack C-tile via LDS, store coalesced -----------------
    const int proj = bn >> 10;                  // uniform per block
    const int b = bm >> 11;
    const int bh = b * 8 + ((bn & 1023) >> 7);
    const int tbase = bm & 2047;

    __syncthreads();                            // staging reads done
    if (proj == 2) {
        // V: LDS T[dl][tl] (transpose), pack r-pairs (consecutive tl)
#pragma unroll
        for (int mi = 0; mi < 4; ++mi) {
#pragma unroll
            for (int ni = 0; ni < 4; ++ni) {
                int dl = wc * 64 + ni * 16 + l15;
                int tlb = wr * 64 + mi * 16 + lk * 4;
                int byte0 = (dl * 256 + tlb * 2) ^ ((dl & 7) << 4);
                *(uint32_t*)(Sb + byte0)     = pack_bf16(acc[mi][ni][0], acc[mi][ni][1]);
                *(uint32_t*)(Sb + byte0 + 4) = pack_bf16(acc[mi][ni][2], acc[mi][ni][3]);
            }
        }
    } else {
        // K/Q: LDS T[tl][dl]
#pragma unroll
        for (int mi = 0; mi < 4; ++mi) {
#pragma unroll
            for (int ni = 0; ni < 4; ++ni) {
                int dl = wc * 64 + ni * 16 + l15;
#pragma unroll
                for (int r = 0; r < 4; ++r) {
                    int tl = wr * 64 + mi * 16 + lk * 4 + r;
                    *(short*)(Sb + ((tl * 256 + dl * 2) ^ ((tl & 7) << 4))) = f2bf(acc[mi][ni][r]);
                }
            }
        }
    }
    __syncthreads();

    short* dst;
    if (proj == 2)
        dst = qkv + (size_t)2 * (32 * 2048 * 128) + (size_t)bh * 128 * 2048;
    else
        dst = qkv + (size_t)proj * (32 * 2048 * 128) + (size_t)bh * 2048 * 128;

#pragma unroll
    for (int i = 0; i < 8; ++i) {
        int c = i * 256 + tid;                  // 0..2047 16B chunks
        int row = c >> 4;
        uint4 v = *(const uint4*)(Sb + row * 256 + (((c & 15) * 16) ^ ((row & 7) << 4)));
        if (proj == 2) {
            // row = d, cols = t
            *(uint4*)(dst + (size_t)row * 2048 + tbase + (c & 15) * 8) = v;
        } else {
            // row = t, cols = d
            *(uint4*)(dst + (size_t)(tbase + row) * 128 + (c & 15) * 8) = v;
        }
    }
}

// ---------------------------------------------------------------------------
// Kernel 3: causal flash attention — single-barrier quad-buffer pipeline.
// R0-R4 model: per-iter wall ~= 2.2k cyc fixed (2x barrier+vmcnt rendezvous)
// + ~75 cyc/KB staged, independent of occupancy/compute.  Attack the fixed
// term: FOUR 32-KB buffers, ONE s_barrier per iteration.
//   iter j: stage(j+3) -> buf (j+3)&3   [overwrites buf (j-1)&3; its readers
//             (compute j-1) all finished before barrier B_{j-1} -> safe]
//           compute tile j              [published at B_{j-1}]
//           vmcnt(8)                    [own loads of tile j+1 done; tiles
//             j+2,j+3 stay in flight — counted, never drained in-loop]
//           s_barrier B_j               [publishes tile j+1 for all waves]
// Staging/read layouts are R0's verified ones (coalesced 1KB/wave global
// reads, 16-slot XOR swizzle, zero bank conflicts) — undoes R4's frag-major
// regression (64 cache lines per staging instruction).
// Geometry from R4 (verified): 256 blocks x 512 thr, uniform 34 iters via
// strips a then 15-a, 8 waves = 4 q-chunks x 2 kv-halves, bh%8 = XCD,
// end-of-strip LDS flash combine.  Dynamic LDS 131072 B (4 x {K16K|V16K});
// combine aliases buf0/1 (ex 64K @0, ml 2K @64K). 1 block/CU.
// ---------------------------------------------------------------------------
__device__ inline void stage64(const short* __restrict__ Kp,
                               const short* __restrict__ Vp,
                               int j0, char* smem, int buf)
{
    short* kls = (short*)(smem + (buf << 15));   // 32 KB per buffer
    short* vls = kls + 8192;                     // +16 KB (shorts)
    const int tid = threadIdx.x;                 // 512 threads
#pragma unroll
    for (int i = 0; i < 2; ++i) {
        int c = i * 512 + tid;                  // 0..1023, 16B chunk index
        int lin = c * 16;                       // linear byte in 16 KB tile
        // K tile: 64 rows x 256 B, 16-slot swizzle (R0 layout)
        int rk = lin >> 8;
        int kof = ((lin & 255) ^ ((rk & 15) << 4)) >> 1;
        __builtin_amdgcn_global_load_lds(
            (const AS1 void*)(Kp + (size_t)(j0 + rk) * 128 + kof),
            (AS3 void*)(kls + c * 8), 16, 0, 0);
        // V tile: 64 pair-rows x 256 B (r holds d=2r lo, d=2r+1 hi) (R0 layout)
        int rv = lin >> 8;
        int p = (lin & 255) ^ ((rv & 15) << 4);
        int d = rv * 2 + (p >> 7);
        int t = (p & 127) >> 1;
        __builtin_amdgcn_global_load_lds(
            (const AS1 void*)(Vp + (size_t)d * 2048 + j0 + t),
            (AS3 void*)(vls + c * 8), 16, 0, 0);
    }
}

__global__ __launch_bounds__(512, 2)
void attn_kernel(const short* __restrict__ qkv, float* __restrict__ out)
{
    extern __shared__ char smem[];
    const int tid = threadIdx.x, lane = tid & 63, wave = tid >> 6;
    const int l31 = lane & 31;
    const int hh_ = lane >> 5;

    const int bh = blockIdx.x & 31;             // bh%8 = XCD under round-robin
    const int a = blockIdx.x >> 5;              // 0..7

    const int qc = wave & 3;                    // q sub-block (32 rows)
    const int kvh = wave >> 2;                  // kv half of staged 64-kv tile

    const size_t HSTRIDE = (size_t)2048 * 128;
    const short* Kp = qkv + (size_t)bh * HSTRIDE;                    // [t][d]
    const short* Qp = qkv + (size_t)32 * HSTRIDE + (size_t)bh * HSTRIDE;
    const short* Vp = qkv + (size_t)64 * HSTRIDE + (size_t)bh * HSTRIDE; // [d][t]

    for (int sidx = 0; sidx < 2; ++sidx) {
        const int sp = sidx ? (15 - a) : a;     // strip index 0..15
        const int q0 = sp * 128;
        const int nt = 2 * sp + 2;              // 64-kv tiles
        const int qwave = q0 + qc * 32;
        const int qglob = qwave + l31;

        __syncthreads();                        // LDS free (prev combine done)

        // Q B-operand frags
        bf16x8 qf[8];
        {
            const short* qrow = Qp + (size_t)(q0 + qc * 32 + l31) * 128 + hh_ * 8;
#pragma unroll
            for (int dblk = 0; dblk < 8; ++dblk)
                qf[dblk] = *(const bf16x8*)(qrow + dblk * 16);
        }

        float mrow = -1e30f, lrow = 0.f;
        f32x16 acco[4] = {};                    // O[q(reg)][dt*32 + l31]

        // prologue: stage up to 3 tiles, publish tile 0
        stage64(Kp, Vp, 0, smem, 0);
        if (nt > 1) stage64(Kp, Vp, 64, smem, 1);
        if (nt > 2) stage64(Kp, Vp, 128, smem, 2);
        if (nt > 2)      { asm volatile("s_waitcnt vmcnt(8)" ::: "memory"); }
        else             { asm volatile("s_waitcnt vmcnt(4)" ::: "memory"); }
        __builtin_amdgcn_sched_barrier(0);
        __builtin_amdgcn_s_barrier();           // tile 0 visible to all waves
        __builtin_amdgcn_sched_barrier(0);

        for (int jt = 0; jt < nt; ++jt) {
            const int j0 = jt << 6;
            // stage tile jt+3 (overwrites buffer released at B_{jt-1})
            if (jt + 3 < nt)
                stage64(Kp, Vp, (jt + 3) << 6, smem, (jt + 3) & 3);

            const int kv0 = j0 + kvh * 32;      // this wave's 32-kv window
            if (kv0 <= qwave + 31) {            // wave-uniform causal gate
                const char* Kb = smem + ((size_t)(jt & 3) << 15);
                const char* Vb = Kb + 16384;

                // S'^T = K Q'^T : lane pair (l, l^32) holds S'[kv][q=l31]
                f32x16 sacc = {};
                const int krow = kvh * 32 + l31;
                __builtin_amdgcn_s_setprio(1);
#pragma unroll
                for (int dblk = 0; dblk < 8; ++dblk) {
                    bf16x8 kf = *(const bf16x8*)(Kb + ((krow * 256 + dblk * 32 + hh_ * 16) ^ ((krow & 15) << 4)));
                    sacc = MFMA32(kf, qf[dblk], sacc);
                }
                __builtin_amdgcn_s_setprio(0);

                // causal mask: only the straddle window (kv0 == qwave)
                if (kv0 + 31 > qwave) {
#pragma unroll
                    for (int r = 0; r < 16; ++r) {
                        int kvglob = kv0 + (r & 3) + 8 * (r >> 2) + 4 * hh_;
                        if (kvglob > qglob) sacc[r] = -1e30f;
                    }
                }

                // row max: in-lane tree + 1 cross-half shuffle
                float pmax = -1e30f;
#pragma unroll
                for (int r = 0; r < 16; r += 4) {
                    float a2 = fmaxf(sacc[r], sacc[r + 1]);
                    float b2 = fmaxf(sacc[r + 2], sacc[r + 3]);
                    pmax = fmaxf(pmax, fmaxf(a2, b2));
                }
                pmax = fmaxf(pmax, __shfl_xor(pmax, 32));

                // defer-max: rescale only when max grew by > 8 nats
                if (!__all(pmax - mrow <= 11.5416f)) {
                    float mn = fmaxf(mrow, pmax);
                    float alpha = __builtin_amdgcn_exp2f(mrow - mn);
                    mrow = mn;
                    lrow *= alpha;
#pragma unroll
                    for (int r = 0; r < 16; ++r) {
                        float ar = __shfl(alpha, (r & 3) + 8 * (r >> 2) + 4 * hh_);
#pragma unroll
                        for (int dt = 0; dt < 4; ++dt) acco[dt][r] *= ar;
                    }
                }

                // P = exp2(S' - m'), row sum, pack to bf16 pairs
                float psum = 0.f;
                uint32_t pkA[4], pkB[4];
#pragma unroll
                for (int sg = 0; sg < 4; ++sg) {
                    float p0 = __builtin_amdgcn_exp2f(sacc[4 * sg + 0] - mrow);
                    float p1 = __builtin_amdgcn_exp2f(sacc[4 * sg + 1] - mrow);
                    float p2 = __builtin_amdgcn_exp2f(sacc[4 * sg + 2] - mrow);
                    float p3 = __builtin_amdgcn_exp2f(sacc[4 * sg + 3] - mrow);
                    psum += (p0 + p1) + (p2 + p3);
                    pkA[sg] = pack_bf16(p0, p1);
                    pkB[sg] = pack_bf16(p2, p3);
                }
                psum += __shfl_xor(psum, 32);
                lrow += psum;

                // O += P V  (P A-frags assembled via cross-half swaps)
                __builtin_amdgcn_s_setprio(1);
#pragma unroll
                for (int kb = 0; kb < 2; ++kb) {
                    uint32_t r0, r1, r2, r3;
                    SWAP32(r0, r2, pkA[2 * kb], pkA[2 * kb + 1]);
                    SWAP32(r1, r3, pkB[2 * kb], pkB[2 * kb + 1]);
                    union { uint32_t u[4]; bf16x8 v; } pa;
                    pa.u[0] = r0; pa.u[1] = r1; pa.u[2] = r2; pa.u[3] = r3;
                    const int slot = kvh * 2 + kb;   // 16-kv slot in 64-kv tile
#pragma unroll
                    for (int dt = 0; dt < 4; ++dt) {
                        int d = dt * 32 + l31;
                        int r = d >> 1;
                        int inner = ((d & 1) << 7) + slot * 32 + hh_ * 16;
                        bf16x8 vf = *(const bf16x8*)(Vb + (r * 256 + (inner ^ ((r & 15) << 4))));
                        acco[dt] = MFMA32(pa.v, vf, acco[dt]);
                    }
                }
                __builtin_amdgcn_s_setprio(0);
            }

            // single rendezvous: publish tile jt+1, release buf jt&3
            if (jt + 1 < nt) {
                if (jt + 4 <= nt)      { asm volatile("s_waitcnt vmcnt(8)" ::: "memory"); }
                else if (jt + 3 == nt) { asm volatile("s_waitcnt vmcnt(4)" ::: "memory"); }
                else                   { asm volatile("s_waitcnt vmcnt(0)" ::: "memory"); }
                __builtin_amdgcn_sched_barrier(0);
                __builtin_amdgcn_s_barrier();
                __builtin_amdgcn_sched_barrier(0);
            }
        }

        // ---- intra-block flash combine: merge kv halves (waves w, w+4) ----
        __syncthreads();                        // all waves done reading LDS
        float* ex = (float*)smem;               // 4 chunks x 4096 f32 (64 KB)
        float* ml = (float*)(smem + 65536);     // 4 chunks x 64 x {m,l} (2 KB)
        if (kvh == 1) {
            float* dst = ex + qc * 4096;
#pragma unroll
            for (int dt = 0; dt < 4; ++dt)
#pragma unroll
                for (int r = 0; r < 16; ++r)
                    dst[(dt * 16 + r) * 64 + lane] = acco[dt][r];
            ml[qc * 128 + lane * 2 + 0] = mrow;
            ml[qc * 128 + lane * 2 + 1] = lrow;
        }
        __syncthreads();
        if (kvh == 0) {
            float m1 = ml[qc * 128 + lane * 2 + 0];
            float l1 = ml[qc * 128 + lane * 2 + 1];
            float M  = fmaxf(mrow, m1);
            float av = __builtin_amdgcn_exp2f(mrow - M);
            float bv = __builtin_amdgcn_exp2f(m1 - M);  // 0 if half empty
            float lf = lrow * av + l1 * bv;
            float sA = av / lf, sB = bv / lf;
            const float* src = ex + qc * 4096;
            const int bb = bh >> 3, hd = bh & 7;
#pragma unroll
            for (int r = 0; r < 16; ++r) {
                int ql = (r & 3) + 8 * (r >> 2) + 4 * hh_;
                float sa = __shfl(sA, ql);
                float sb = __shfl(sB, ql);
                int t = qwave + ql;
                float* o = out + (size_t)(bb * 2048 + t) * 1024 + hd * 128 + l31;
#pragma unroll
                for (int dt = 0; dt < 4; ++dt)
                    o[dt * 32] = acco[dt][r] * sa + src[(dt * 16 + r) * 64 + lane] * sb;
            }
        }
        // drain output stores so next strip's counted vmcnt isn't polluted
        asm volatile("s_waitcnt vmcnt(0)" ::: "memory");
    }
}

// ---------------------------------------------------------------------------
extern "C" void kernel_launch(void* const* d_in, const int* in_sizes, int n_in,
                              void* d_out, int out_size, void* d_ws, size_t ws_size,
                              hipStream_t stream) {
    const float* x  = (const float*)d_in[0];
    const float* w  = (const float*)d_in[1];
    const float* bK = (const float*)d_in[2];
    const float* bQ = (const float*)d_in[3];
    const float* bV = (const float*)d_in[4];

    // workspace layout (bytes): xb 8,388,608 | W 3,145,728 | qkv 50,331,648
    short* xb  = (short*)d_ws;
    short* W   = (short*)((char*)d_ws + 8388608);
    short* qkv = (short*)((char*)d_ws + 8388608 + 3145728);
    float* out = (float*)d_out;

    // allow 128 KB dynamic LDS (idempotent; not a stream op, capture-safe)
    hipFuncSetAttribute((const void*)attn_kernel,
                        hipFuncAttributeMaxDynamicSharedMemorySize, 131072);

    prep_kernel<<<2048, 256, 0, stream>>>(x, w, bK, bQ, bV, xb, W);
    proj_gemm<<<64 * 24, 256, 0, stream>>>(xb, W, qkv);
    attn_kernel<<<256, 512, 131072, stream>>>(qkv, out);
}

// Round 6
// 100.001 us; speedup vs baseline: 2.2493x; 1.0785x over previous
//
#include <hip/hip_runtime.h>
#include <hip/hip_bf16.h>
#include <stdint.h>

typedef __attribute__((ext_vector_type(8))) short bf16x8;
typedef __attribute__((ext_vector_type(4))) float f32x4;
typedef __attribute__((ext_vector_type(16))) float f32x16;

#define MFMA16(a,b,c) __builtin_amdgcn_mfma_f32_16x16x32_bf16((a),(b),(c),0,0,0)
#define MFMA32(a,b,c) __builtin_amdgcn_mfma_f32_32x32x16_bf16((a),(b),(c),0,0,0)
#define AS1 __attribute__((address_space(1)))
#define AS3 __attribute__((address_space(3)))

__device__ inline short f2bf(float f) {
    union { __hip_bfloat16 h; short s; } u;
    u.h = __float2bfloat16(f);
    return u.s;
}
__device__ inline uint32_t pack_bf16(float a, float b) {
    union { __hip_bfloat16 h; uint16_t u; } ua, ub;
    ua.h = __float2bfloat16(a); ub.h = __float2bfloat16(b);
    return (uint32_t)ua.u | ((uint32_t)ub.u << 16);
}

// cross-half register exchange
#if __has_builtin(__builtin_amdgcn_permlane32_swap)
#define SWAP32(x, y, a, b) { auto _r = __builtin_amdgcn_permlane32_swap((a),(b),false,false); \
                             (x) = _r[0]; (y) = _r[1]; }
#else
#define SWAP32(x, y, a, b) { uint32_t _ta = __shfl_xor((uint32_t)(a),32); \
                             uint32_t _tb = __shfl_xor((uint32_t)(b),32); \
                             (x) = hh_ ? _tb : (a); (y) = hh_ ? (b) : _ta; }
#endif

// S' = S * scale * log2(e): fold into Wq so attention exp is native exp2.
#define QSCALE 0.12751879523879295f   // (1/sqrt(128)) * log2(e)

// ---------------------------------------------------------------------------
// Kernel 1: eff-weight mix -> bf16 W [3][8][128][512]; x f32 -> bf16
// ---------------------------------------------------------------------------
#define NW (8*128*512)        // 524288 per projection
#define NX4 (8192*512/4)      // 1048576 float4 chunks of x

__global__ void prep_kernel(const float* __restrict__ x,
                            const float* __restrict__ w,
                            const float* __restrict__ bK,
                            const float* __restrict__ bQ,
                            const float* __restrict__ bV,
                            short* __restrict__ xb,    // [8192][512]
                            short* __restrict__ W)     // [3][1024][512]  (K,Q,V)
{
    const float w0 = w[0], w1 = w[1], w2 = w[2], w3 = w[3];
    for (int i = blockIdx.x * blockDim.x + threadIdx.x; i < NW + NX4;
         i += gridDim.x * blockDim.x) {
        if (i < NW) {
            int e = i & 511;
            int d = (i >> 9) & 127;
            int h = i >> 16;
            float eff = 0.f;
            if (h < 4) { eff += w2; if (d < 64 && e < 256) eff += w0; }
            if (d < 32 && e < 256) eff += w1;
            if (d < 64) eff += w3;
            W[i]          = f2bf(eff * bK[i]);
            W[i + NW]     = f2bf(eff * bQ[i] * QSCALE);
            W[i + 2*NW]   = f2bf(eff * bV[i]);
        } else {
            int j = i - NW;
            float4 v = ((const float4*)x)[j];
            short4 o;
            o.x = f2bf(v.x); o.y = f2bf(v.y); o.z = f2bf(v.z); o.w = f2bf(v.w);
            ((short4*)xb)[j] = o;
        }
    }
}

// ---------------------------------------------------------------------------
// Kernel 2: C[8192,3072] = xb[8192,512] @ W[3072,512]^T
// K,Q stored [bh][t][d]; V stored TRANSPOSED as [bh][d][t].
// LDS-repacked coalesced epilogue; bijective XCD grid swizzle.
// ---------------------------------------------------------------------------
__global__ __launch_bounds__(256)
void proj_gemm(const short* __restrict__ A,    // [8192][512]
               const short* __restrict__ Bw,   // [3072][512]
               short* __restrict__ qkv)
{
    __shared__ short S[128 * 128];             // 32 KB: staging + repack
    short* As = S;                             // 16 KB
    short* Bs = S + 128 * 64;                  // 16 KB
    const int tid = threadIdx.x;
    const int lane = tid & 63;
    const int wave = tid >> 6;
    const int wr = wave >> 1, wc = wave & 1;
    const int l15 = lane & 15, lk = lane >> 4;

    // bijective XCD swizzle: 1536 blocks, 192 consecutive per XCD
    const int wg = (blockIdx.x & 7) * 192 + (blockIdx.x >> 3);
    const int bm = (wg / 24) * 128;
    const int bn = (wg % 24) * 128;

    char* Ab = (char*)As;
    char* Bb = (char*)Bs;
    char* Sb = (char*)S;
    f32x4 acc[4][4] = {};

    for (int k0 = 0; k0 < 512; k0 += 64) {
        __syncthreads();
#pragma unroll
        for (int i = 0; i < 4; ++i) {
            int c = i * 256 + tid;              // 0..1023, 16B chunk
            int lin = c * 16;                   // linear byte in 16 KB tile
            int row = lin >> 7;                 // 0..127
            int cof = ((lin & 127) ^ ((row & 7) << 4)) >> 1;   // shorts
            __builtin_amdgcn_global_load_lds(
                (const AS1 void*)(A + (size_t)(bm + row) * 512 + k0 + cof),
                (AS3 void*)(As + c * 8), 16, 0, 0);
            __builtin_amdgcn_global_load_lds(
                (const AS1 void*)(Bw + (size_t)(bn + row) * 512 + k0 + cof),
                (AS3 void*)(Bs + c * 8), 16, 0, 0);
        }
        __syncthreads();                        // drains vmcnt(0) (m97 pattern)
#pragma unroll
        for (int kk = 0; kk < 2; ++kk) {
            bf16x8 af[4], bfv[4];
#pragma unroll
            for (int mi = 0; mi < 4; ++mi) {
                int row = wr * 64 + mi * 16 + l15;
                af[mi] = *(const bf16x8*)(Ab + ((row * 128 + kk * 64 + lk * 16) ^ ((row & 7) << 4)));
            }
#pragma unroll
            for (int ni = 0; ni < 4; ++ni) {
                int row = wc * 64 + ni * 16 + l15;
                bfv[ni] = *(const bf16x8*)(Bb + ((row * 128 + kk * 64 + lk * 16) ^ ((row & 7) << 4)));
            }
#pragma unroll
            for (int mi = 0; mi < 4; ++mi)
#pragma unroll
                for (int ni = 0; ni < 4; ++ni)
                    acc[mi][ni] = MFMA16(af[mi], bfv[ni], acc[mi][ni]);
        }
    }

    // ---- epilogue: repack C-tile via LDS, store coalesced -----------------
    const int proj = bn >> 10;                  // uniform per block
    const int b = bm >> 11;
    const int bh = b * 8 + ((bn & 1023) >> 7);
    const int tbase = bm & 2047;

    __syncthreads();                            // staging reads done
    if (proj == 2) {
        // V: LDS T[dl][tl] (transpose), pack r-pairs (consecutive tl)
#pragma unroll
        for (int mi = 0; mi < 4; ++mi) {
#pragma unroll
            for (int ni = 0; ni < 4; ++ni) {
                int dl = wc * 64 + ni * 16 + l15;
                int tlb = wr * 64 + mi * 16 + lk * 4;
                int byte0 = (dl * 256 + tlb * 2) ^ ((dl & 7) << 4);
                *(uint32_t*)(Sb + byte0)     = pack_bf16(acc[mi][ni][0], acc[mi][ni][1]);
                *(uint32_t*)(Sb + byte0 + 4) = pack_bf16(acc[mi][ni][2], acc[mi][ni][3]);
            }
        }
    } else {
        // K/Q: LDS T[tl][dl]
#pragma unroll
        for (int mi = 0; mi < 4; ++mi) {
#pragma unroll
            for (int ni = 0; ni < 4; ++ni) {
                int dl = wc * 64 + ni * 16 + l15;
#pragma unroll
                for (int r = 0; r < 4; ++r) {
                    int tl = wr * 64 + mi * 16 + lk * 4 + r;
                    *(short*)(Sb + ((tl * 256 + dl * 2) ^ ((tl & 7) << 4))) = f2bf(acc[mi][ni][r]);
                }
            }
        }
    }
    __syncthreads();

    short* dst;
    if (proj == 2)
        dst = qkv + (size_t)2 * (32 * 2048 * 128) + (size_t)bh * 128 * 2048;
    else
        dst = qkv + (size_t)proj * (32 * 2048 * 128) + (size_t)bh * 2048 * 128;

#pragma unroll
    for (int i = 0; i < 8; ++i) {
        int c = i * 256 + tid;                  // 0..2047 16B chunks
        int row = c >> 4;
        uint4 v = *(const uint4*)(Sb + row * 256 + (((c & 15) * 16) ^ ((row & 7) << 4)));
        if (proj == 2) {
            // row = d, cols = t
            *(uint4*)(dst + (size_t)row * 2048 + tbase + (c & 15) * 8) = v;
        } else {
            // row = t, cols = d
            *(uint4*)(dst + (size_t)(tbase + row) * 128 + (c & 15) * 8) = v;
        }
    }
}

// ---------------------------------------------------------------------------
// Kernel 3: causal flash attention — KVBLK=128, halved iteration count.
// R5 post-mortem: barrier/vmcnt restructuring is a dead end (71.3->68.7);
// per-iteration cost is dominated by per-tile-visit WORK (VALU 30% biggest
// pipe: staging addr math, softmax fixed parts, chain stalls), phase-locked
// across waves. Lever: amortize it — 128-kv tiles (same total staged bytes,
// HALF the iterations: 17/block instead of 34), and hoist all staging
// address math out of the loop (per-thread offsets are tid-only; src addr
// = base + j0*stride, one add per load).
// Inner loop = R0's verified 64-kv-per-wave structure (sacc[2], 16+16 MFMA32
// per wave per tile), applied to kv-half kvh of the 128-kv tile; V tile =
// two R0-style 16KB subtiles (sub = kvh). Geometry = R5's verified frame:
// 256 blocks x 8 waves (4 qc x 2 kvh), strips a & 15-a -> uniform 17 iters,
// bh%8 = XCD, per-strip LDS flash combine.
// Dynamic LDS 131072 B: 2 buffers x {K 32K | V 2x16K}. 1 block/CU,
// 2 waves/SIMD. Double buffer, drain vmcnt(0) at iteration end (issue-to-
// wait distance = 1 full iteration >> L2 latency).
// ---------------------------------------------------------------------------
__global__ __launch_bounds__(512, 2)
void attn_kernel(const short* __restrict__ qkv, float* __restrict__ out)
{
    extern __shared__ char smem[];
    const int tid = threadIdx.x, lane = tid & 63, wave = tid >> 6;
    const int l31 = lane & 31;
    const int hh_ = lane >> 5;

    const int bh = blockIdx.x & 31;             // bh%8 = XCD under round-robin
    const int a = blockIdx.x >> 5;              // 0..7

    const int qc = wave & 3;                    // q sub-block (32 rows)
    const int kvh = wave >> 2;                  // kv half of staged 128-kv tile

    const size_t HSTRIDE = (size_t)2048 * 128;
    const short* Kp = qkv + (size_t)bh * HSTRIDE;                    // [t][d]
    const short* Qp = qkv + (size_t)32 * HSTRIDE + (size_t)bh * HSTRIDE;
    const short* Vp = qkv + (size_t)64 * HSTRIDE + (size_t)bh * HSTRIDE; // [d][t]

    // ---- hoisted staging offsets (tid-only; computed once) ----------------
    // K tile: 128 rows x 256 B, 16-slot XOR swizzle (R0 layout, 2x rows)
    // V tile: 2 subtiles (t-halves) x {64 pair-rows x 256 B} (R0 layout)
    int koffs[4], voffs[4];
#pragma unroll
    for (int i = 0; i < 4; ++i) {
        int c = i * 512 + tid;                  // 0..2047, 16B chunk index
        int rk = c >> 4;                        // K row 0..127
        int kof = (((c * 16) & 255) ^ ((rk & 15) << 4)) >> 1;
        koffs[i] = rk * 128 + kof;              // + j0*128 at stage time
        int sub = c >> 10, cc = c & 1023;       // V subtile, chunk within
        int rv = cc >> 4;                       // pair-row 0..63
        int p = ((cc * 16) & 255) ^ ((rv & 15) << 4);
        int d = 2 * rv + (p >> 7);
        int t = (p & 127) >> 1;
        voffs[i] = d * 2048 + sub * 64 + t;     // + j0 at stage time
    }

#define STAGE128(J0, BUF) {                                                   \
        char* _b = smem + ((BUF) << 16);                                      \
        _Pragma("unroll")                                                     \
        for (int i = 0; i < 4; ++i) {                                         \
            int c = i * 512 + tid;                                            \
            __builtin_amdgcn_global_load_lds(                                 \
                (const AS1 void*)(Kp + koffs[i] + (J0) * 128),                \
                (AS3 void*)(_b + c * 16), 16, 0, 0);                          \
            __builtin_amdgcn_global_load_lds(                                 \
                (const AS1 void*)(Vp + voffs[i] + (J0)),                      \
                (AS3 void*)(_b + 32768 + c * 16), 16, 0, 0);                  \
        }                                                                     \
    }

    for (int sidx = 0; sidx < 2; ++sidx) {
        const int sp = sidx ? (15 - a) : a;     // strip index 0..15
        const int q0 = sp * 128;
        const int nt = sp + 1;                  // 128-kv tiles
        const int qwave = q0 + qc * 32;
        const int qglob = qwave + l31;

        __syncthreads();                        // LDS free (prev combine done)

        // Q B-operand frags
        bf16x8 qf[8];
        {
            const short* qrow = Qp + (size_t)(q0 + qc * 32 + l31) * 128 + hh_ * 8;
#pragma unroll
            for (int dblk = 0; dblk < 8; ++dblk)
                qf[dblk] = *(const bf16x8*)(qrow + dblk * 16);
        }

        float mrow = -1e30f, lrow = 0.f;
        f32x16 acco[4] = {};                    // O[q(reg)][dt*32 + l31]

        STAGE128(0, 0);                         // prologue: tile 0 -> buf 0
        asm volatile("s_waitcnt vmcnt(0)" ::: "memory");
        __builtin_amdgcn_sched_barrier(0);
        __builtin_amdgcn_s_barrier();           // tile 0 visible to all waves
        __builtin_amdgcn_sched_barrier(0);

        for (int jt = 0; jt < nt; ++jt) {
            const int j0 = jt << 7;
            if (jt + 1 < nt)
                STAGE128((jt + 1) << 7, (jt + 1) & 1);

            const int kv0 = j0 + kvh * 64;      // this wave's 64-kv window
            if (kv0 <= qwave + 31) {            // wave-uniform causal gate
                const char* Kb = smem + ((jt & 1) << 16);
                const char* Vb = Kb + 32768 + (kvh << 14);   // sub = kvh

                // S'^T = K Q'^T : lane pair (l, l^32) holds S'[kv][q=l31]
                f32x16 sacc[2] = {};
                __builtin_amdgcn_s_setprio(1);
#pragma unroll
                for (int dblk = 0; dblk < 8; ++dblk) {
#pragma unroll
                    for (int kvt = 0; kvt < 2; ++kvt) {
                        int krow = kvh * 64 + kvt * 32 + l31;
                        bf16x8 kf = *(const bf16x8*)(Kb + krow * 256 +
                            ((dblk * 32 + hh_ * 16) ^ ((krow & 15) << 4)));
                        sacc[kvt] = MFMA32(kf, qf[dblk], sacc[kvt]);
                    }
                }
                __builtin_amdgcn_s_setprio(0);

                // causal mask: only the straddle tile
                if (kv0 + 63 > qwave) {
#pragma unroll
                    for (int kvt = 0; kvt < 2; ++kvt)
#pragma unroll
                        for (int r = 0; r < 16; ++r) {
                            int kvglob = kv0 + kvt * 32 + (r & 3) + 8 * (r >> 2) + 4 * hh_;
                            if (kvglob > qglob) sacc[kvt][r] = -1e30f;
                        }
                }

                // row max: in-lane tree + 1 cross-half shuffle
                float pmax = -1e30f;
#pragma unroll
                for (int kvt = 0; kvt < 2; ++kvt)
#pragma unroll
                    for (int r = 0; r < 16; r += 4) {
                        float a2 = fmaxf(sacc[kvt][r], sacc[kvt][r + 1]);
                        float b2 = fmaxf(sacc[kvt][r + 2], sacc[kvt][r + 3]);
                        pmax = fmaxf(pmax, fmaxf(a2, b2));
                    }
                pmax = fmaxf(pmax, __shfl_xor(pmax, 32));

                // defer-max: rescale only when max grew by > 8 nats
                if (!__all(pmax - mrow <= 11.5416f)) {
                    float mn = fmaxf(mrow, pmax);
                    float alpha = __builtin_amdgcn_exp2f(mrow - mn);
                    mrow = mn;
                    lrow *= alpha;
#pragma unroll
                    for (int r = 0; r < 16; ++r) {
                        float ar = __shfl(alpha, (r & 3) + 8 * (r >> 2) + 4 * hh_);
#pragma unroll
                        for (int dt = 0; dt < 4; ++dt) acco[dt][r] *= ar;
                    }
                }

                // P = exp2(S' - m'), row sum, pack to bf16 pairs
                float psum = 0.f;
                uint32_t pkA[2][4], pkB[2][4];
#pragma unroll
                for (int kvt = 0; kvt < 2; ++kvt)
#pragma unroll
                    for (int sg = 0; sg < 4; ++sg) {
                        float p0 = __builtin_amdgcn_exp2f(sacc[kvt][4 * sg + 0] - mrow);
                        float p1 = __builtin_amdgcn_exp2f(sacc[kvt][4 * sg + 1] - mrow);
                        float p2 = __builtin_amdgcn_exp2f(sacc[kvt][4 * sg + 2] - mrow);
                        float p3 = __builtin_amdgcn_exp2f(sacc[kvt][4 * sg + 3] - mrow);
                        psum += (p0 + p1) + (p2 + p3);
                        pkA[kvt][sg] = pack_bf16(p0, p1);
                        pkB[kvt][sg] = pack_bf16(p2, p3);
                    }
                psum += __shfl_xor(psum, 32);
                lrow += psum;

                // O += P V  (P A-frags assembled via cross-half swaps)
                __builtin_amdgcn_s_setprio(1);
#pragma unroll
                for (int w = 0; w < 4; ++w) {   // 16-kv slot within 64-kv half
                    const int kvt = w >> 1, kbl = w & 1;
                    uint32_t r0, r1, r2, r3;
                    SWAP32(r0, r2, pkA[kvt][2 * kbl], pkA[kvt][2 * kbl + 1]);
                    SWAP32(r1, r3, pkB[kvt][2 * kbl], pkB[kvt][2 * kbl + 1]);
                    union { uint32_t u[4]; bf16x8 v; } pa;
                    pa.u[0] = r0; pa.u[1] = r1; pa.u[2] = r2; pa.u[3] = r3;
#pragma unroll
                    for (int dt = 0; dt < 4; ++dt) {
                        int d = dt * 32 + l31;
                        int r = d >> 1;
                        int inner = ((d & 1) << 7) + w * 32 + hh_ * 16;
                        bf16x8 vf = *(const bf16x8*)(Vb + r * 256 + (inner ^ ((r & 15) << 4)));
                        acco[dt] = MFMA32(pa.v, vf, acco[dt]);
                    }
                }
                __builtin_amdgcn_s_setprio(0);
            }

            if (jt + 1 < nt) {
                asm volatile("s_waitcnt vmcnt(0)" ::: "memory");  // tile jt+1 landed
                __builtin_amdgcn_sched_barrier(0);
                __builtin_amdgcn_s_barrier();   // publish tile jt+1, release buf
                __builtin_amdgcn_sched_barrier(0);
            }
        }

        // ---- intra-block flash combine: merge kv halves (waves w, w+4) ----
        __syncthreads();                        // all waves done reading LDS
        float* ex = (float*)smem;               // 4 chunks x 4096 f32 (64 KB)
        float* ml = (float*)(smem + 65536);     // 4 chunks x 64 x {m,l} (2 KB)
        if (kvh == 1) {
            float* dst = ex + qc * 4096;
#pragma unroll
            for (int dt = 0; dt < 4; ++dt)
#pragma unroll
                for (int r = 0; r < 16; ++r)
                    dst[(dt * 16 + r) * 64 + lane] = acco[dt][r];
            ml[qc * 128 + lane * 2 + 0] = mrow;
            ml[qc * 128 + lane * 2 + 1] = lrow;
        }
        __syncthreads();
        if (kvh == 0) {
            float m1 = ml[qc * 128 + lane * 2 + 0];
            float l1 = ml[qc * 128 + lane * 2 + 1];
            float M  = fmaxf(mrow, m1);
            float av = __builtin_amdgcn_exp2f(mrow - M);
            float bv = __builtin_amdgcn_exp2f(m1 - M);  // 0 if half empty
            float lf = lrow * av + l1 * bv;
            float sA = av / lf, sB = bv / lf;
            const float* src = ex + qc * 4096;
            const int bb = bh >> 3, hd = bh & 7;
#pragma unroll
            for (int r = 0; r < 16; ++r) {
                int ql = (r & 3) + 8 * (r >> 2) + 4 * hh_;
                float sa = __shfl(sA, ql);
                float sb = __shfl(sB, ql);
                int t = qwave + ql;
                float* o = out + (size_t)(bb * 2048 + t) * 1024 + hd * 128 + l31;
#pragma unroll
                for (int dt = 0; dt < 4; ++dt)
                    o[dt * 32] = acco[dt][r] * sa + src[(dt * 16 + r) * 64 + lane] * sb;
            }
        }
        // drain combine stores before next strip's staging/waits
        asm volatile("s_waitcnt vmcnt(0)" ::: "memory");
    }
#undef STAGE128
}

// ---------------------------------------------------------------------------
extern "C" void kernel_launch(void* const* d_in, const int* in_sizes, int n_in,
                              void* d_out, int out_size, void* d_ws, size_t ws_size,
                              hipStream_t stream) {
    const float* x  = (const float*)d_in[0];
    const float* w  = (const float*)d_in[1];
    const float* bK = (const float*)d_in[2];
    const float* bQ = (const float*)d_in[3];
    const float* bV = (const float*)d_in[4];

    // workspace layout (bytes): xb 8,388,608 | W 3,145,728 | qkv 50,331,648
    short* xb  = (short*)d_ws;
    short* W   = (short*)((char*)d_ws + 8388608);
    short* qkv = (short*)((char*)d_ws + 8388608 + 3145728);
    float* out = (float*)d_out;

    // allow 128 KB dynamic LDS (idempotent; not a stream op, capture-safe)
    hipFuncSetAttribute((const void*)attn_kernel,
                        hipFuncAttributeMaxDynamicSharedMemorySize, 131072);

    prep_kernel<<<2048, 256, 0, stream>>>(x, w, bK, bQ, bV, xb, W);
    proj_gemm<<<64 * 24, 256, 0, stream>>>(xb, W, qkv);
    attn_kernel<<<256, 512, 131072, stream>>>(qkv, out);
}